// Round 8
// baseline (647.642 us; speedup 1.0000x reference)
//
#include <hip/hip_runtime.h>
#include <hip/hip_bf16.h>

// Problem: B=8,H=8 (BH=64), LQ=LK=1024, D=64. fp32 inputs.
// d_out = [output (64*1024*64) | attention (64*1024*1024)] fp32.
// bf16 MFMA for QK^T and PV; target = memory-bound on mask read (256MB) +
// attention write (256MB). R4: 64KB LDS / 2 blk/CU -> latency-bound, 240us.
// R7: QT=8 (32KB LDS, 5 blk/CU) + mask register-prefetch hoisted over QK^T.

typedef float  f32x4  __attribute__((ext_vector_type(4)));
typedef int    i32x4  __attribute__((ext_vector_type(4)));
typedef short  bf16x8 __attribute__((ext_vector_type(8)));
typedef short  s16x4  __attribute__((ext_vector_type(4)));
typedef short  s16x8  __attribute__((ext_vector_type(8)));

#define BH 64
#define LQN 1024
#define LKN 1024
#define DD 64
#define QT 8
// LDS: S[QT][1024] f32 = 32KB exactly -> 5 blocks/CU (160KB pool)
#define SMEM_BYTES (QT * LKN * 4)
// byte address into swizzled S: row stride 4096B, XOR bits 4..6 with row&7
#define SADDR(row, cb) (((row) << 12) + ((cb) ^ (((row) & 7) << 4)))

static __device__ __forceinline__ short f2bf(float f) {
  unsigned u = __float_as_uint(f);
  unsigned r = (u + 0x7fffu + ((u >> 16) & 1u)) >> 16;  // RNE
  return (short)r;
}

// ---- pre-kernel 1: K fp32 -> bf16 (same layout) ----
__global__ void cvt_k(const float* __restrict__ K, short* __restrict__ Kbf) {
  int i = blockIdx.x * 256 + threadIdx.x;  // 1M f32x4 exactly
  f32x4 v = ((const f32x4*)K)[i];
  s16x4 o;
  o[0] = f2bf(v[0]); o[1] = f2bf(v[1]); o[2] = f2bf(v[2]); o[3] = f2bf(v[3]);
  ((s16x4*)Kbf)[i] = o;
}

// ---- pre-kernel 2: V fp32 [bh][k][d] -> bf16 transposed Vt [bh][d][k] ----
__global__ void cvt_v(const float* __restrict__ V, short* __restrict__ Vt) {
  __shared__ float tile[64][65];
  int bh = blockIdx.x >> 4, kt = blockIdx.x & 15;  // 16 k-tiles of 64
  int t = threadIdx.x;
  const float* src = V + ((size_t)bh * LKN + kt * 64) * DD;
  for (int j = 0; j < 4; ++j) {
    int f = t + j * 256;  // f32x4 index within 64x64 tile
    f32x4 v = *(const f32x4*)(src + f * 4);
    int r = f >> 4, c = (f & 15) * 4;
    tile[r][c] = v[0]; tile[r][c + 1] = v[1]; tile[r][c + 2] = v[2]; tile[r][c + 3] = v[3];
  }
  __syncthreads();
  int d = t >> 2, kc = (t & 3) * 16;
  short* dst = Vt + ((size_t)(bh * DD + d)) * LKN + kt * 64 + kc;
  s16x8 o0, o1;
  for (int j = 0; j < 8; ++j) {
    o0[j] = f2bf(tile[kc + j][d]);
    o1[j] = f2bf(tile[kc + 8 + j][d]);
  }
  *(s16x8*)dst = o0;
  *(s16x8*)(dst + 8) = o1;
}

// ---- main attention kernel: one block = (bh, 8 q rows) ----
__global__ __launch_bounds__(256, 5) void attn(
    const float* __restrict__ Qf, const short* __restrict__ Kbf,
    const short* __restrict__ Vt, const int* __restrict__ mask,
    const float* __restrict__ qmask, float* __restrict__ out,
    float* __restrict__ att) {
  extern __shared__ char smem[];
  int bh = blockIdx.x >> 7;             // 128 q-tiles per bh
  int q0 = (blockIdx.x & 127) * QT;
  int w = threadIdx.x >> 6, l = threadIdx.x & 63;
  int lr = l & 15, lg = l >> 4;

  // Q A-frags from fp32, scale 1/8 folded in. A row = lr; only rows 0..7
  // are real (lr>=8 duplicates row lr&7; its outputs are never stored).
  bf16x8 qa[2];
  {
    const float* qrow = Qf + ((size_t)(bh * LQN + q0 + (lr & 7))) * DD + lg * 8;
    for (int t = 0; t < 2; ++t) {
      f32x4 a = *(const f32x4*)(qrow + t * 32);
      f32x4 b = *(const f32x4*)(qrow + t * 32 + 4);
      bf16x8 q;
      for (int j = 0; j < 4; ++j) { q[j] = f2bf(a[j] * 0.125f); q[4 + j] = f2bf(b[j] * 0.125f); }
      qa[t] = q;
    }
  }

  // ---- mask register-prefetch (same addresses softmax uses); HBM latency
  // overlaps the whole QK^T phase. 8 x int4 = 32 VGPRs.
  i32x4 pm[2][4];
#pragma unroll
  for (int rr = 0; rr < 2; ++rr) {
    const int* mrow = mask + ((size_t)(bh * LQN + q0 + w * 2 + rr)) * LKN;
#pragma unroll
    for (int j = 0; j < 4; ++j)
      pm[rr][j] = *(const i32x4*)(mrow + 4 * (l + 64 * j));
  }

  // ---- QK^T: wave w owns k-subtiles ks = w*16 .. w*16+15 (16 cols each) ----
  for (int ks = w * 16; ks < w * 16 + 16; ++ks) {
    int kb = ks * 16;
    const short* krow = Kbf + ((size_t)(bh * LKN + kb + lr)) * DD + lg * 8;
    bf16x8 k0 = *(const bf16x8*)(krow);
    bf16x8 k1 = *(const bf16x8*)(krow + 32);
    f32x4 acc = {0.f, 0.f, 0.f, 0.f};
    acc = __builtin_amdgcn_mfma_f32_16x16x32_bf16(qa[0], k0, acc, 0, 0, 0);
    acc = __builtin_amdgcn_mfma_f32_16x16x32_bf16(qa[1], k1, acc, 0, 0, 0);
    // D layout: col = lane&15, row = 4*(lane>>4) + r; keep rows 0..7 (lg<2)
    if (lg < 2)
      for (int r = 0; r < 4; ++r)
        *(float*)(smem + SADDR(lg * 4 + r, (kb + lr) * 4)) = acc[r];
  }
  __syncthreads();

  // ---- softmax: wave w owns rows w*2 .. w*2+1; row spread over 64 lanes ----
#pragma unroll
  for (int rr = 0; rr < 2; ++rr) {
    int row = w * 2 + rr;
    f32x4 v[4];
    float mx = -3.4e38f;
#pragma unroll
    for (int j = 0; j < 4; ++j) {
      v[j] = *(f32x4*)(smem + SADDR(row, 16 * (l + 64 * j)));
      i32x4 m4 = pm[rr][j];  // prefetched mask
      for (int c = 0; c < 4; ++c) v[j][c] = m4[c] ? v[j][c] : -1e9f;
      mx = fmaxf(mx, fmaxf(fmaxf(v[j][0], v[j][1]), fmaxf(v[j][2], v[j][3])));
    }
    for (int off = 32; off; off >>= 1) mx = fmaxf(mx, __shfl_xor(mx, off));
    float sum = 0.f;
    for (int j = 0; j < 4; ++j)
      for (int c = 0; c < 4; ++c) { v[j][c] = __expf(v[j][c] - mx); sum += v[j][c]; }
    for (int off = 32; off; off >>= 1) sum += __shfl_xor(sum, off);
    float qm = qmask[bh * LQN + q0 + row];   // query_mask [B,H,1,LQ]
    float scale = qm / sum;
    float* arow = att + ((size_t)(bh * LQN + q0 + row)) * LKN;
    for (int j = 0; j < 4; ++j) {
      f32x4 o = v[j] * scale;                                  // normalized P
      *(f32x4*)(smem + SADDR(row, 16 * (l + 64 * j))) = o;     // P for PV
      *(f32x4*)(arow + 4 * (l + 64 * j)) = o;                  // attention out
    }
  }
  __syncthreads();

  // ---- PV: wave w = d-subtile (cols w*16 .. +15); A from LDS P, B from Vt
  f32x4 acc = {0.f, 0.f, 0.f, 0.f};
  const short* vrow = Vt + ((size_t)(bh * DD + w * 16 + lr)) * LKN;
  for (int kt = 0; kt < 32; ++kt) {
    int cb = kt * 128 + lg * 32;
    f32x4 lo = *(f32x4*)(smem + SADDR(lr & 7, cb));
    f32x4 hi = *(f32x4*)(smem + SADDR(lr & 7, cb + 16));
    bf16x8 a;
    for (int j = 0; j < 4; ++j) { a[j] = f2bf(lo[j]); a[4 + j] = f2bf(hi[j]); }
    bf16x8 b = *(const bf16x8*)(vrow + kt * 32 + lg * 8);
    acc = __builtin_amdgcn_mfma_f32_16x16x32_bf16(a, b, acc, 0, 0, 0);
  }
  if (lg < 2)
    for (int r = 0; r < 4; ++r) {
      int row = lg * 4 + r;
      out[((size_t)(bh * LQN + q0 + row)) * DD + w * 16 + lr] = acc[r];
    }
}

extern "C" void kernel_launch(void* const* d_in, const int* in_sizes, int n_in,
                              void* d_out, int out_size, void* d_ws, size_t ws_size,
                              hipStream_t stream) {
  const float* Q = (const float*)d_in[0];
  const float* K = (const float*)d_in[1];
  const float* V = (const float*)d_in[2];
  const int* mask = (const int*)d_in[3];
  const float* qmask = (const float*)d_in[4];
  float* out = (float*)d_out;                       // [BH,1024,64]
  float* att = out + (size_t)BH * LQN * DD;         // [BH,1024,1024]
  short* Kbf = (short*)d_ws;                        // 8MB
  short* Vt = Kbf + (size_t)BH * LKN * DD;          // 8MB (needs ws >= 16MB)

  cvt_k<<<4096, 256, 0, stream>>>(K, Kbf);
  cvt_v<<<1024, 256, 0, stream>>>(V, Vt);
  attn<<<BH * (LQN / QT), 256, SMEM_BYTES, stream>>>(Q, Kbf, Vt, mask, qmask, out, att);
}

// Round 10
// 555.850 us; speedup vs baseline: 1.1651x; 1.1651x over previous
//
#include <hip/hip_runtime.h>
#include <hip/hip_bf16.h>

// Problem: B=8,H=8 (BH=64), LQ=LK=1024, D=64. fp32 inputs.
// d_out = [output (64*1024*64) | attention (64*1024*1024)] fp32.
// R4 (QT=16, 4 waves): 240us. R8 (QT=8, 5 blk/CU): 302us REGRESSION ->
// bottleneck is per-block serial path, not occupancy. R9: QT=16, 512 thr
// (8 waves): QK^T 8 iters/wave, softmax 2 rows/wave, PV k-split 16 iters/wave
// + LDS pair-reduction. No duplicate work, path ~halved.

typedef float  f32x4  __attribute__((ext_vector_type(4)));
typedef int    i32x4  __attribute__((ext_vector_type(4)));
typedef short  bf16x8 __attribute__((ext_vector_type(8)));
typedef short  s16x4  __attribute__((ext_vector_type(4)));
typedef short  s16x8  __attribute__((ext_vector_type(8)));

#define BH 64
#define LQN 1024
#define LKN 1024
#define DD 64
#define QT 16
// LDS: S[16][1024] f32 = 64KB -> 2 blocks/CU (128KB of 160KB pool)
#define SMEM_BYTES (QT * LKN * 4)
// byte address into swizzled S: row stride 4096B, XOR bits 4..6 with row&7
#define SADDR(row, cb) (((row) << 12) + ((cb) ^ (((row) & 7) << 4)))

static __device__ __forceinline__ short f2bf(float f) {
  unsigned u = __float_as_uint(f);
  unsigned r = (u + 0x7fffu + ((u >> 16) & 1u)) >> 16;  // RNE
  return (short)r;
}

// ---- pre-kernel 1: K fp32 -> bf16 (same layout) ----
__global__ void cvt_k(const float* __restrict__ K, short* __restrict__ Kbf) {
  int i = blockIdx.x * 256 + threadIdx.x;  // 1M f32x4 exactly
  f32x4 v = ((const f32x4*)K)[i];
  s16x4 o;
  o[0] = f2bf(v[0]); o[1] = f2bf(v[1]); o[2] = f2bf(v[2]); o[3] = f2bf(v[3]);
  ((s16x4*)Kbf)[i] = o;
}

// ---- pre-kernel 2: V fp32 [bh][k][d] -> bf16 transposed Vt [bh][d][k] ----
__global__ void cvt_v(const float* __restrict__ V, short* __restrict__ Vt) {
  __shared__ float tile[64][65];
  int bh = blockIdx.x >> 4, kt = blockIdx.x & 15;  // 16 k-tiles of 64
  int t = threadIdx.x;
  const float* src = V + ((size_t)bh * LKN + kt * 64) * DD;
  for (int j = 0; j < 4; ++j) {
    int f = t + j * 256;  // f32x4 index within 64x64 tile
    f32x4 v = *(const f32x4*)(src + f * 4);
    int r = f >> 4, c = (f & 15) * 4;
    tile[r][c] = v[0]; tile[r][c + 1] = v[1]; tile[r][c + 2] = v[2]; tile[r][c + 3] = v[3];
  }
  __syncthreads();
  int d = t >> 2, kc = (t & 3) * 16;
  short* dst = Vt + ((size_t)(bh * DD + d)) * LKN + kt * 64 + kc;
  s16x8 o0, o1;
  for (int j = 0; j < 8; ++j) {
    o0[j] = f2bf(tile[kc + j][d]);
    o1[j] = f2bf(tile[kc + 8 + j][d]);
  }
  *(s16x8*)dst = o0;
  *(s16x8*)(dst + 8) = o1;
}

// ---- main attention kernel: one block = (bh, 16 q rows), 8 waves ----
__global__ __launch_bounds__(512, 4) void attn(
    const float* __restrict__ Qf, const short* __restrict__ Kbf,
    const short* __restrict__ Vt, const int* __restrict__ mask,
    const float* __restrict__ qmask, float* __restrict__ out,
    float* __restrict__ att) {
  extern __shared__ char smem[];
  int bh = blockIdx.x >> 6;             // 64 q-tiles per bh
  int q0 = (blockIdx.x & 63) * QT;
  int w = threadIdx.x >> 6, l = threadIdx.x & 63;   // w = 0..7
  int lr = l & 15, lg = l >> 4;

  // Q A-frags from fp32, scale 1/8 folded in: A[m=lr][k=t*32+lg*8+e]
  bf16x8 qa[2];
  {
    const float* qrow = Qf + ((size_t)(bh * LQN + q0 + lr)) * DD + lg * 8;
    for (int t = 0; t < 2; ++t) {
      f32x4 a = *(const f32x4*)(qrow + t * 32);
      f32x4 b = *(const f32x4*)(qrow + t * 32 + 4);
      bf16x8 q;
      for (int j = 0; j < 4; ++j) { q[j] = f2bf(a[j] * 0.125f); q[4 + j] = f2bf(b[j] * 0.125f); }
      qa[t] = q;
    }
  }

  // mask prefetch for softmax rows w*2, w*2+1 (compiler may sink; harmless)
  i32x4 pm[2][4];
#pragma unroll
  for (int rr = 0; rr < 2; ++rr) {
    const int* mrow = mask + ((size_t)(bh * LQN + q0 + w * 2 + rr)) * LKN;
#pragma unroll
    for (int j = 0; j < 4; ++j)
      pm[rr][j] = *(const i32x4*)(mrow + 4 * (l + 64 * j));
  }

  // ---- QK^T: wave w owns k-subtiles ks = w*8 .. w*8+7 (8 iters) ----
#pragma unroll 4
  for (int i = 0; i < 8; ++i) {
    int kb = (w * 8 + i) * 16;
    const short* krow = Kbf + ((size_t)(bh * LKN + kb + lr)) * DD + lg * 8;
    bf16x8 k0 = *(const bf16x8*)(krow);
    bf16x8 k1 = *(const bf16x8*)(krow + 32);
    f32x4 acc = {0.f, 0.f, 0.f, 0.f};
    acc = __builtin_amdgcn_mfma_f32_16x16x32_bf16(qa[0], k0, acc, 0, 0, 0);
    acc = __builtin_amdgcn_mfma_f32_16x16x32_bf16(qa[1], k1, acc, 0, 0, 0);
    // D layout: col = lane&15, row = 4*(lane>>4) + r  [guide m89/m91]
    for (int r = 0; r < 4; ++r)
      *(float*)(smem + SADDR(lg * 4 + r, (kb + lr) * 4)) = acc[r];
  }
  __syncthreads();

  // ---- softmax: wave w owns rows w*2 .. w*2+1; row spread over 64 lanes ----
#pragma unroll
  for (int rr = 0; rr < 2; ++rr) {
    int row = w * 2 + rr;
    f32x4 v[4];
    float mx = -3.4e38f;
#pragma unroll
    for (int j = 0; j < 4; ++j) {
      v[j] = *(f32x4*)(smem + SADDR(row, 16 * (l + 64 * j)));
      i32x4 m4 = pm[rr][j];
      for (int c = 0; c < 4; ++c) v[j][c] = m4[c] ? v[j][c] : -1e9f;
      mx = fmaxf(mx, fmaxf(fmaxf(v[j][0], v[j][1]), fmaxf(v[j][2], v[j][3])));
    }
    for (int off = 32; off; off >>= 1) mx = fmaxf(mx, __shfl_xor(mx, off));
    float sum = 0.f;
    for (int j = 0; j < 4; ++j)
      for (int c = 0; c < 4; ++c) { v[j][c] = __expf(v[j][c] - mx); sum += v[j][c]; }
    for (int off = 32; off; off >>= 1) sum += __shfl_xor(sum, off);
    float qm = qmask[bh * LQN + q0 + row];   // query_mask [B,H,1,LQ]
    float scale = qm / sum;
    float* arow = att + ((size_t)(bh * LQN + q0 + row)) * LKN;
    for (int j = 0; j < 4; ++j) {
      f32x4 o = v[j] * scale;                                  // normalized P
      *(f32x4*)(smem + SADDR(row, 16 * (l + 64 * j))) = o;     // P for PV
      *(f32x4*)(arow + 4 * (l + 64 * j)) = o;                  // attention out
    }
  }
  __syncthreads();

  // ---- PV k-split: h = w>>2 owns k-half, ws = w&3 owns d-cols ws*16..+15
  int h = w >> 2, ws = w & 3;
  f32x4 acc = {0.f, 0.f, 0.f, 0.f};
  const short* vrow = Vt + ((size_t)(bh * DD + ws * 16 + lr)) * LKN;
#pragma unroll 4
  for (int kt = 0; kt < 16; ++kt) {
    int ktg = h * 16 + kt;
    int cb = ktg * 128 + lg * 32;
    f32x4 lo = *(f32x4*)(smem + SADDR(lr, cb));
    f32x4 hi = *(f32x4*)(smem + SADDR(lr, cb + 16));
    bf16x8 a;
    for (int j = 0; j < 4; ++j) { a[j] = f2bf(lo[j]); a[4 + j] = f2bf(hi[j]); }
    bf16x8 b = *(const bf16x8*)(vrow + ktg * 32 + lg * 8);
    acc = __builtin_amdgcn_mfma_f32_16x16x32_bf16(a, b, acc, 0, 0, 0);
  }
  __syncthreads();              // all P reads from S complete
  if (h == 1)                   // upper k-half waves park partial sums
    *(f32x4*)(smem + ((ws * 64 + l) << 4)) = acc;
  __syncthreads();
  if (h == 0) {
    f32x4 other = *(f32x4*)(smem + ((ws * 64 + l) << 4));
    acc += other;
    for (int r = 0; r < 4; ++r) {
      int row = lg * 4 + r;
      out[((size_t)(bh * LQN + q0 + row)) * DD + ws * 16 + lr] = acc[r];
    }
  }
}

extern "C" void kernel_launch(void* const* d_in, const int* in_sizes, int n_in,
                              void* d_out, int out_size, void* d_ws, size_t ws_size,
                              hipStream_t stream) {
  const float* Q = (const float*)d_in[0];
  const float* K = (const float*)d_in[1];
  const float* V = (const float*)d_in[2];
  const int* mask = (const int*)d_in[3];
  const float* qmask = (const float*)d_in[4];
  float* out = (float*)d_out;                       // [BH,1024,64]
  float* att = out + (size_t)BH * LQN * DD;         // [BH,1024,1024]
  short* Kbf = (short*)d_ws;                        // 8MB
  short* Vt = Kbf + (size_t)BH * LKN * DD;          // 8MB (needs ws >= 16MB)

  cvt_k<<<4096, 256, 0, stream>>>(K, Kbf);
  cvt_v<<<1024, 256, 0, stream>>>(V, Vt);
  attn<<<BH * (LQN / QT), 512, SMEM_BYTES, stream>>>(Q, Kbf, Vt, mask, qmask, out, att);
}